// Round 1
// baseline (196.401 us; speedup 1.0000x reference)
//
#include <hip/hip_runtime.h>

// DINOMIMICClassification: per-sample 3-layer expert MLP (E=16,B=512,D=1536,H=768,T=2).
// Expert-grouped GEMM (only the selected expert runs per sample): memory-bound on
// streaming W1 (75.5MB) + W2 (37.7MB) once. fp32 VALU compute hides under the stream.

namespace {
constexpr int NE = 16, NB = 512, ND = 1536, NH = 768;
constexpr int CT = 64;          // columns per block tile
constexpr int KT = 32;          // k rows per LDS stage
constexpr int NCT = NH / CT;    // 12 column tiles

// Computes part[ks][b][c0..c0+63] = sum_{k in ks-range} act[b][k] * W[e_b][k][c]
// (no bias/relu here — partials are combined downstream).
template<int DIN, int KS>
__global__ __launch_bounds__(256)
void grouped_mm(const float* __restrict__ act,   // [NB][DIN]
                const int*   __restrict__ head_idx,
                const float* __restrict__ W,     // [NE][DIN][NH]
                float*       __restrict__ part)  // [KS][NB][NH]
{
    constexpr int KLEN = DIN / KS;
    const int bid = blockIdx.x;
    const int e   = bid / (NCT * KS);
    const int rem = bid % (NCT * KS);
    const int j   = rem / KS;
    const int ks  = rem % KS;
    const int tid = threadIdx.x;

    __shared__ int lst[NB];
    __shared__ int n_sh;
    // wave 0 builds this expert's sample list via ballot-compact
    if (tid < 64) {
        int cnt = 0;
        for (int base = 0; base < NB; base += 64) {
            const int h = head_idx[base + tid];
            const unsigned long long m = __ballot(h == e);
            const int pos = cnt + __popcll(m & ((1ull << tid) - 1ull));
            if (h == e) lst[pos] = base + tid;
            cnt += __popcll(m);
        }
        if (tid == 0) n_sh = cnt;
    }
    __syncthreads();
    const int n = n_sh;
    if (n == 0) return;

    const int c0 = j * CT;
    const int k0 = ks * KLEN;
    const float* Wp   = W + ((size_t)e * DIN) * NH;
    float*       outp = part + ((size_t)ks * NB) * NH;

    __shared__ float Ws[KT][CT];   // [k][c] — inner-loop read: uniform k, contiguous c
    __shared__ float Xs[KT][64];   // [k][s] — inner-loop read: uniform k, contiguous s

    const int cg = tid & 15;   // col group: cols cg*4..+3
    const int sg = tid >> 4;   // sample group: samples sg*4..+3

    for (int s0 = 0; s0 < n; s0 += 64) {
        float acc[4][4];
        #pragma unroll
        for (int i = 0; i < 4; ++i)
            #pragma unroll
            for (int q = 0; q < 4; ++q) acc[i][q] = 0.f;

        for (int kt = 0; kt < KLEN; kt += KT) {
            __syncthreads();
            {   // stage W tile: 32 rows x 64 cols, 256B contiguous per row
                const int kk = tid >> 4;          // 0..15
                const int cc = (tid & 15) * 4;
                const float* g = Wp + (size_t)(k0 + kt + kk) * NH + c0 + cc;
                const float4 v0 = *(const float4*)g;
                const float4 v1 = *(const float4*)(g + (size_t)16 * NH);
                *(float4*)&Ws[kk][cc]      = v0;
                *(float4*)&Ws[kk + 16][cc] = v1;
            }
            {   // stage X transposed: Xs[k][s]
                const int s  = tid & 63;
                const int kq = tid >> 6;          // 0..3 -> k = kq*8 .. +7
                if (s0 + s < n) {
                    const float* g = act + (size_t)lst[s0 + s] * DIN + k0 + kt + kq * 8;
                    const float4 v0 = *(const float4*)g;
                    const float4 v1 = *(const float4*)(g + 4);
                    Xs[kq*8+0][s] = v0.x; Xs[kq*8+1][s] = v0.y;
                    Xs[kq*8+2][s] = v0.z; Xs[kq*8+3][s] = v0.w;
                    Xs[kq*8+4][s] = v1.x; Xs[kq*8+5][s] = v1.y;
                    Xs[kq*8+6][s] = v1.z; Xs[kq*8+7][s] = v1.w;
                } else {
                    #pragma unroll
                    for (int i = 0; i < 8; ++i) Xs[kq*8+i][s] = 0.f;
                }
            }
            __syncthreads();
            #pragma unroll
            for (int k = 0; k < KT; ++k) {
                const float4 wv = *(const float4*)&Ws[k][cg * 4];
                const float4 xv = *(const float4*)&Xs[k][sg * 4];
                acc[0][0] += xv.x*wv.x; acc[0][1] += xv.x*wv.y; acc[0][2] += xv.x*wv.z; acc[0][3] += xv.x*wv.w;
                acc[1][0] += xv.y*wv.x; acc[1][1] += xv.y*wv.y; acc[1][2] += xv.y*wv.z; acc[1][3] += xv.y*wv.w;
                acc[2][0] += xv.z*wv.x; acc[2][1] += xv.z*wv.y; acc[2][2] += xv.z*wv.z; acc[2][3] += xv.z*wv.w;
                acc[3][0] += xv.w*wv.x; acc[3][1] += xv.w*wv.y; acc[3][2] += xv.w*wv.z; acc[3][3] += xv.w*wv.w;
            }
        }
        #pragma unroll
        for (int si = 0; si < 4; ++si) {
            const int s = s0 + sg * 4 + si;
            if (s < n) {
                float* o = outp + (size_t)lst[s] * NH + c0 + cg * 4;
                *(float4*)o = make_float4(acc[si][0], acc[si][1], acc[si][2], acc[si][3]);
            }
        }
    }
}

// h1[b][c] = relu(b1[e_b][c] + sum_ks part[ks][b][c]), vectorized float4
__global__ __launch_bounds__(256)
void combine_relu(const float* __restrict__ part,   // [4][NB][NH]
                  const float* __restrict__ bias,   // [NE][NH]
                  const int*   __restrict__ head_idx,
                  float*       __restrict__ outp)   // [NB][NH]
{
    const int i = blockIdx.x * 256 + threadIdx.x;    // float4 index
    if (i >= NB * NH / 4) return;
    const int b  = i / (NH / 4);
    const int c4 = i % (NH / 4);
    constexpr int STR = NB * NH / 4;
    const float4* P = (const float4*)part;
    const float4 v0 = P[i], v1 = P[i + STR], v2 = P[i + 2*STR], v3 = P[i + 3*STR];
    const int e = head_idx[b];
    const float4 bb = ((const float4*)bias)[e * (NH / 4) + c4];
    float4 o;
    o.x = fmaxf(v0.x + v1.x + v2.x + v3.x + bb.x, 0.f);
    o.y = fmaxf(v0.y + v1.y + v2.y + v3.y + bb.y, 0.f);
    o.z = fmaxf(v0.z + v1.z + v2.z + v3.z + bb.z, 0.f);
    o.w = fmaxf(v0.w + v1.w + v2.w + v3.w + bb.w, 0.f);
    ((float4*)outp)[i] = o;
}

// out[b][t] = relu(sum_ks h2p[ks][b][:] + b2[e]) . W3[e][:,t] + b3[e][t]
__global__ __launch_bounds__(64)
void final_head(const float* __restrict__ h2p,  // [4][NB][NH]
                const float* __restrict__ b2,   // [NE][NH]
                const float* __restrict__ W3,   // [NE][NH][2]
                const float* __restrict__ b3,   // [NE][2]
                const int*   __restrict__ head_idx,
                float*       __restrict__ out)  // [NB][2]
{
    const int b    = blockIdx.x;
    const int lane = threadIdx.x;
    const int e    = head_idx[b];
    constexpr size_t STR = (size_t)NB * NH;
    float a0 = 0.f, a1 = 0.f;
    for (int h = lane; h < NH; h += 64) {
        const size_t o = (size_t)b * NH + h;
        float s = h2p[o] + h2p[STR + o] + h2p[2*STR + o] + h2p[3*STR + o] + b2[e * NH + h];
        s = fmaxf(s, 0.f);
        const float2 w = *(const float2*)&W3[((size_t)e * NH + h) * 2];
        a0 += s * w.x;
        a1 += s * w.y;
    }
    #pragma unroll
    for (int off = 32; off > 0; off >>= 1) {
        a0 += __shfl_down(a0, off);
        a1 += __shfl_down(a1, off);
    }
    if (lane == 0) {
        out[b * 2 + 0] = a0 + b3[e * 2 + 0];
        out[b * 2 + 1] = a1 + b3[e * 2 + 1];
    }
}
} // namespace

extern "C" void kernel_launch(void* const* d_in, const int* in_sizes, int n_in,
                              void* d_out, int out_size, void* d_ws, size_t ws_size,
                              hipStream_t stream) {
    const float* x   = (const float*)d_in[0];
    const int*   hi  = (const int*)  d_in[1];
    const float* W1  = (const float*)d_in[2];
    const float* b1  = (const float*)d_in[3];
    const float* W2  = (const float*)d_in[4];
    const float* b2  = (const float*)d_in[5];
    const float* W3  = (const float*)d_in[6];
    const float* b3  = (const float*)d_in[7];
    float* out = (float*)d_out;

    // ws layout (fp32): h1p [4][B][H] | h1 [B][H] | h2p [4][B][H]  (~14.2 MB)
    float* h1p = (float*)d_ws;
    float* h1  = h1p + (size_t)4 * NB * NH;
    float* h2p = h1  + (size_t)NB * NH;

    grouped_mm<ND, 4><<<NE * NCT * 4, 256, 0, stream>>>(x,  hi, W1, h1p);
    combine_relu<<<(NB * NH / 4 + 255) / 256, 256, 0, stream>>>(h1p, b1, hi, h1);
    grouped_mm<NH, 4><<<NE * NCT * 4, 256, 0, stream>>>(h1, hi, W2, h2p);
    final_head<<<NB, 64, 0, stream>>>(h2p, b2, W3, b3, hi, out);
}